// Round 1
// 551.892 us; speedup vs baseline: 1.2495x; 1.2495x over previous
//
#include <hip/hip_runtime.h>
#include <hip/hip_bf16.h>

typedef __bf16 bf16x8 __attribute__((ext_vector_type(8)));
typedef float f32x4 __attribute__((ext_vector_type(4)));
typedef unsigned short ushort_t;

#define LOG2E      1.4426950408889634f
#define SELU_SCALE 1.0507009873554805f
#define SELU_ALPHA 1.6732632423543772f
#define HST 136   // ushorts per node row in per-wave H staging (272B, 16B-aligned)

__device__ __forceinline__ float fexp2(float x){ return __builtin_amdgcn_exp2f(x); }
__device__ __forceinline__ float frcp (float x){ return __builtin_amdgcn_rcpf(x); }
__device__ __forceinline__ float tanh_fast(float x){
  return 1.0f - 2.0f * frcp(fexp2(x * (2.0f * LOG2E)) + 1.0f);
}
__device__ __forceinline__ float sigmoid_fast(float x){
  return frcp(1.0f + fexp2(-LOG2E * x));
}
__device__ __forceinline__ float selu_fast(float x){
  float e = SELU_ALPHA * (fexp2(LOG2E * x) - 1.0f);
  return SELU_SCALE * (x > 0.0f ? x : e);
}
__device__ __forceinline__ unsigned short f2bf(float f){
  unsigned u = __builtin_bit_cast(unsigned, f);
  u += 0x7fffu + ((u >> 16) & 1u);          // RNE
  return (unsigned short)(u >> 16);
}
__device__ __forceinline__ unsigned pk2(float a, float b){
#if __has_builtin(__builtin_amdgcn_cvt_pk_bf16_f32)
  typedef __bf16 bf2 __attribute__((ext_vector_type(2)));
  union { bf2 v; unsigned u; } c;
  c.v = __builtin_amdgcn_cvt_pk_bf16_f32(a, b);
  return c.u;
#else
  unsigned ua = __builtin_bit_cast(unsigned, a);
  ua += 0x7fffu + ((ua >> 16) & 1u);
  unsigned ub = __builtin_bit_cast(unsigned, b);
  ub += 0x7fffu + ((ub >> 16) & 1u);
  return (ua >> 16) | (ub & 0xffff0000u);
#endif
}
__device__ __forceinline__ bf16x8 pack8(float4 a, float4 b){
  union { bf16x8 v; unsigned u[4]; } c;
  c.u[0] = pk2(a.x, a.y); c.u[1] = pk2(a.z, a.w);
  c.u[2] = pk2(b.x, b.y); c.u[3] = pk2(b.z, b.w);
  return c.v;
}
__device__ __forceinline__ int imin(int a, int b){ return a < b ? a : b; }

// largest g in [lo,hi] with offs[g] <= n  (range-narrowed binary search)
__device__ __forceinline__ int find_graph(const int* __restrict__ offs, int lo, int hi, int n){
  while (lo < hi){
    int mid = (lo + hi + 1) >> 1;
    if (offs[mid] <= n) lo = mid; else hi = mid - 1;
  }
  return lo;
}

// blocks 0..191: weight transpose/fold/bf16-convert; block 192: prefix scan;
// blocks 193.. : zero pooled (gidz_kernel eliminated — gid computed in fused kernel)
__global__ __launch_bounds__(256) void prep_kernel(
    const float* __restrict__ i1w, const float* __restrict__ j1w,
    const float* __restrict__ i2w, const float* __restrict__ j2w,
    ushort_t* __restrict__ wi1t, ushort_t* __restrict__ wj1t,
    ushort_t* __restrict__ wi2t, ushort_t* __restrict__ wj2t,
    const int* __restrict__ n_node, int* __restrict__ offs,
    float* __restrict__ pooled, int B){
  if (blockIdx.x >= 193){
    int id = (blockIdx.x - 193) * 256 + threadIdx.x;
    if (id < B * 128) pooled[id] = 0.0f;
    return;
  }
  if (blockIdx.x == 192){
    __shared__ int part[256];
    const int t = threadIdx.x;
    const int chunk = (B + 255) / 256;
    int s = 0;
    for (int i = 0; i < chunk; ++i){ int idx = t * chunk + i; if (idx < B) s += n_node[idx]; }
    part[t] = s;
    __syncthreads();
    if (t == 0){
      int run = 0;
      for (int i = 0; i < 256; ++i){ int v = part[i]; part[i] = run; run += v; }
      offs[B] = run;
    }
    __syncthreads();
    int run = part[t];
    for (int i = 0; i < chunk; ++i){
      int idx = t * chunk + i;
      if (idx < B){ offs[idx] = run; run += n_node[idx]; }
    }
    return;
  }
  int id = blockIdx.x * 256 + threadIdx.x;
  if (id < 8192){
    int n = id >> 6, k = id & 63;
    float v = i1w[k * 128 + n];
    if (k < 2) v += i1w[(64 + k) * 128 + n];     // fold hx dup-columns
    wi1t[n * 64 + k] = f2bf(v);
  } else if (id < 16384){
    int m = id - 8192; int n = m >> 6, k = m & 63;
    float v = j1w[k * 128 + n];
    if (k < 2) v += j1w[(64 + k) * 128 + n];
    wj1t[n * 64 + k] = f2bf(v);
  } else if (id < 32768){
    int m = id - 16384; int n = m >> 7, k = m & 127;
    wi2t[n * 128 + k] = f2bf(i2w[k * 128 + n]);
  } else if (id < 49152){
    int m = id - 32768; int n = m >> 7, k = m & 127;
    wj2t[n * 128 + k] = f2bf(j2w[k * 128 + n]);
  }
}

// One 64-thread block = one wave = 64 nodes (4 sets of 16). No __syncthreads anywhere.
// Weight fragments (96 KB/wave) now amortized over 64 nodes instead of 32.
// graph-id via in-kernel binary search on offs (2 full searches, narrow-range for splits).
// __launch_bounds__(64,2): VGPR cap 256 so compiler can hold Hf (128 VGPR) + prefetch.
__global__ __launch_bounds__(64, 2) void fused_node_kernel(
    const float* __restrict__ nodes, const float* __restrict__ node_mask,
    const int* __restrict__ offs,
    const ushort_t* __restrict__ wi1t, const ushort_t* __restrict__ wj1t,
    const ushort_t* __restrict__ wi2t, const ushort_t* __restrict__ wj2t,
    const float* __restrict__ i1b, const float* __restrict__ i2b,
    const float* __restrict__ j1b, const float* __restrict__ j2b,
    float* __restrict__ pooled, int N, int B){

  __shared__ __align__(16) ushort_t Hs[64 * HST];   // 17408 B, private to this wave

  const int t    = threadIdx.x;
  const int lm   = t & 15;
  const int quad = t >> 4;
  const int n0   = blockIdx.x * 64;

  // ---- graph range for this 64-node tile (issued early; latency hides under L1) ----
  const int wg0 = __builtin_amdgcn_readfirstlane(
                    find_graph(offs, 0, B - 1, imin(n0, N - 1)));
  const int wg1 = __builtin_amdgcn_readfirstlane(
                    find_graph(offs, 0, B - 1, imin(n0 + 63, N - 1)));
  const bool caseA = (wg0 == wg1);

  // ---- node masks (broadcast float4 loads in the common in-range case) ----
  float mk[4][4];
  if (n0 + 63 < N){
    #pragma unroll
    for (int s = 0; s < 4; ++s){
      float4 mv = *(const float4*)(node_mask + n0 + s * 16 + quad * 4);
      mk[s][0] = mv.x; mk[s][1] = mv.y; mk[s][2] = mv.z; mk[s][3] = mv.w;
    }
  } else {
    #pragma unroll
    for (int s = 0; s < 4; ++s)
      #pragma unroll
      for (int r = 0; r < 4; ++r){
        int node = n0 + s * 16 + quad * 4 + r;
        mk[s][r] = (node < N) ? node_mask[node] : 0.0f;
      }
  }

  // ---- node B-fragments: 4 sets x 2 k-tiles ----
  bf16x8 nb[4][2];
  #pragma unroll
  for (int s = 0; s < 4; ++s){
    const int node = imin(n0 + s * 16 + lm, N - 1);
    const float* p = nodes + (size_t)node * 64;
    #pragma unroll
    for (int kb = 0; kb < 2; ++kb){
      float4 q0 = *(const float4*)(p + kb * 32 + quad * 8);
      float4 q1 = *(const float4*)(p + kb * 32 + quad * 8 + 4);
      nb[s][kb] = pack8(q0, q1);
    }
  }

  const f32x4 z4 = {0.f, 0.f, 0.f, 0.f};
  bf16x8 Hf[2][4][4];   // [branch][set][kb] A-operand fragments, 128 VGPR

  // ---- layer 1, both branches sequentially through the same LDS buffer ----
  #pragma unroll
  for (int br = 0; br < 2; ++br){
    const ushort_t* w1 = br ? wj1t : wi1t;
    const float*    b1 = br ? j1b  : i1b;

    #pragma unroll
    for (int mt = 0; mt < 8; ++mt){
      bf16x8 a0 = *(const bf16x8*)(w1 + (mt * 16 + lm) * 64 + quad * 8);
      bf16x8 a1 = *(const bf16x8*)(w1 + (mt * 16 + lm) * 64 + 32 + quad * 8);
      float4 bv = *(const float4*)(b1 + mt * 16 + quad * 4);
      #pragma unroll
      for (int s = 0; s < 4; ++s){
        f32x4 acc = z4;
        acc = __builtin_amdgcn_mfma_f32_16x16x32_bf16(a0, nb[s][0], acc, 0, 0, 0);
        acc = __builtin_amdgcn_mfma_f32_16x16x32_bf16(a1, nb[s][1], acc, 0, 0, 0);
        float v0 = acc[0] + bv.x, v1 = acc[1] + bv.y;
        float v2 = acc[2] + bv.z, v3 = acc[3] + bv.w;
        if (br == 0){
          v0 = tanh_fast(v0); v1 = tanh_fast(v1); v2 = tanh_fast(v2); v3 = tanh_fast(v3);
        } else {
          v0 = selu_fast(v0); v1 = selu_fast(v1); v2 = selu_fast(v2); v3 = selu_fast(v3);
        }
        uint2 w; w.x = pk2(v0, v1); w.y = pk2(v2, v3);
        *(uint2*)(Hs + (size_t)(s * 16 + lm) * HST + mt * 16 + quad * 4) = w;
      }
    }
    // read back this branch's H as A-operand fragments (same-wave DS is in-order)
    #pragma unroll
    for (int s = 0; s < 4; ++s)
      #pragma unroll
      for (int kb = 0; kb < 4; ++kb)
        Hf[br][s][kb] = *(const bf16x8*)(Hs + (size_t)(s * 16 + lm) * HST + kb * 32 + quad * 8);
  }

  // ---- split-tile graph ids (rare path: ~13% of tiles), ranges are ~1 graph wide ----
  int gf[4], gl[4], gr[4][4];
  if (!caseA){
    #pragma unroll
    for (int s = 0; s < 4; ++s){
      gf[s] = __builtin_amdgcn_readfirstlane(
                find_graph(offs, wg0, wg1, imin(n0 + s * 16, N - 1)));
      gl[s] = __builtin_amdgcn_readfirstlane(
                find_graph(offs, wg0, wg1, imin(n0 + s * 16 + 15, N - 1)));
      #pragma unroll
      for (int r = 0; r < 4; ++r)
        gr[s][r] = find_graph(offs, gf[s], gl[s], imin(n0 + s * 16 + quad * 4 + r, N - 1));
    }
  }

  // ---- layer 2, branches interleaved; pooling in registers ----
  float s_pool[8];
  #pragma unroll
  for (int nt = 0; nt < 8; ++nt) s_pool[nt] = 0.0f;

  #pragma unroll
  for (int nt = 0; nt < 8; ++nt){
    const float c2i = i2b[nt * 16 + lm];
    const float c2j = j2b[nt * 16 + lm];
    f32x4 ai[4] = {z4, z4, z4, z4}, aj[4] = {z4, z4, z4, z4};
    #pragma unroll
    for (int kb = 0; kb < 4; ++kb){
      bf16x8 bi = *(const bf16x8*)(wi2t + (nt * 16 + lm) * 128 + kb * 32 + quad * 8);
      bf16x8 bj = *(const bf16x8*)(wj2t + (nt * 16 + lm) * 128 + kb * 32 + quad * 8);
      #pragma unroll
      for (int s = 0; s < 4; ++s){
        ai[s] = __builtin_amdgcn_mfma_f32_16x16x32_bf16(Hf[0][s][kb], bi, ai[s], 0, 0, 0);
        aj[s] = __builtin_amdgcn_mfma_f32_16x16x32_bf16(Hf[1][s][kb], bj, aj[s], 0, 0, 0);
      }
    }
    if (caseA){
      float acc = 0.0f;
      #pragma unroll
      for (int s = 0; s < 4; ++s)
        #pragma unroll
        for (int r = 0; r < 4; ++r){
          float g = sigmoid_fast(ai[s][r] + c2i);
          acc += g * (aj[s][r] + c2j) * mk[s][r];
        }
      s_pool[nt] += acc;
    } else {
      #pragma unroll
      for (int s = 0; s < 4; ++s){
        float vals[4];
        #pragma unroll
        for (int r = 0; r < 4; ++r){
          float g = sigmoid_fast(ai[s][r] + c2i);
          vals[r] = g * (aj[s][r] + c2j) * mk[s][r];
        }
        for (int g = gf[s]; g <= gl[s]; ++g){
          float tt = 0.0f;
          #pragma unroll
          for (int r = 0; r < 4; ++r) tt += (gr[s][r] == g) ? vals[r] : 0.0f;
          tt += __shfl_xor(tt, 16);
          tt += __shfl_xor(tt, 32);
          if (quad == 0) atomicAdd(&pooled[g * 128 + nt * 16 + lm], tt);
        }
      }
    }
  }
  if (caseA){
    #pragma unroll
    for (int nt = 0; nt < 8; ++nt){
      float v = s_pool[nt];
      v += __shfl_xor(v, 16);
      v += __shfl_xor(v, 32);
      if (quad == 0) atomicAdd(&pooled[wg0 * 128 + nt * 16 + lm], v);
    }
  }
}

// head: out[g] = selu(pooled[g] @ h1_w + h1_b) @ h2_w + h2_b   (fp32)
__global__ __launch_bounds__(128) void head_kernel(
    const float* __restrict__ pooled, const float* __restrict__ h1w,
    const float* __restrict__ h1b, const float* __restrict__ h2w,
    const float* __restrict__ h2b, float* __restrict__ out){
  __shared__ float pg[128];
  __shared__ float red[64];
  const int g = blockIdx.x, t = threadIdx.x;
  pg[t] = pooled[g * 128 + t];
  __syncthreads();
  float acc = h1b[t];
  #pragma unroll 8
  for (int k = 0; k < 128; ++k) acc += pg[k] * h1w[k * 128 + t];
  float s = selu_fast(acc) * h2w[t];
  if (t >= 64) red[t - 64] = s;
  __syncthreads();
  if (t < 64){
    float v = s + red[t];
    #pragma unroll
    for (int o = 32; o > 0; o >>= 1) v += __shfl_down(v, o);
    if (t == 0) out[g] = v + h2b[0];
  }
}

extern "C" void kernel_launch(void* const* d_in, const int* in_sizes, int n_in,
                              void* d_out, int out_size, void* d_ws, size_t ws_size,
                              hipStream_t stream){
  const float* nodes     = (const float*)d_in[0];
  const float* node_mask = (const float*)d_in[1];
  const int*   n_node    = (const int*)  d_in[2];
  const float* i1w = (const float*)d_in[3];
  const float* i1b = (const float*)d_in[4];
  const float* i2w = (const float*)d_in[5];
  const float* i2b = (const float*)d_in[6];
  const float* j1w = (const float*)d_in[7];
  const float* j1b = (const float*)d_in[8];
  const float* j2w = (const float*)d_in[9];
  const float* j2b = (const float*)d_in[10];
  const float* h1w = (const float*)d_in[11];
  const float* h1b = (const float*)d_in[12];
  const float* h2w = (const float*)d_in[13];
  const float* h2b = (const float*)d_in[14];
  float* out = (float*)d_out;

  const int N = in_sizes[0] / 64;
  const int B = in_sizes[2];

  char* ws = (char*)d_ws;
  float* pooled = (float*)ws;                                    // B*128 f32
  size_t off = (size_t)B * 128 * 4;
  int* offs = (int*)(ws + off);                                  // B+1 ints
  off += (((size_t)(B + 1) * 4 + 255) & ~(size_t)255);
  ushort_t* wi1t = (ushort_t*)(ws + off);                        // 8192
  ushort_t* wj1t = wi1t + 8192;                                  // 8192
  ushort_t* wi2t = wj1t + 8192;                                  // 16384
  ushort_t* wj2t = wi2t + 16384;                                 // 16384

  int zblk = (B * 128 + 255) / 256;
  prep_kernel<<<193 + zblk, 256, 0, stream>>>(i1w, j1w, i2w, j2w, wi1t, wj1t, wi2t, wj2t,
                                              n_node, offs, pooled, B);

  int nblk = (N + 63) / 64;
  fused_node_kernel<<<nblk, 64, 0, stream>>>(nodes, node_mask, offs,
                                             wi1t, wj1t, wi2t, wj2t,
                                             i1b, i2b, j1b, j2b, pooled, N, B);
  head_kernel<<<B, 128, 0, stream>>>(pooled, h1w, h1b, h2w, h2b, out);
}